// Round 1
// baseline (1156.958 us; speedup 1.0000x reference)
//
#include <hip/hip_runtime.h>

// ---------------------------------------------------------------------------
// TPUGEMMLinear: blockwise-fp8 quantize (block=128) of x[M,K] (along K) and
// w[K,N] (along N), dequant-scaled fp32 GEMM + bias.
// Strategy: quant+dequant both operands to bf16 (exact fp8 round-trip via HW
// cvt, then bf16 RNE), then m97-style bf16 MFMA GEMM on A[M,K] x B^T[N,K].
// Workspace layout: Xd bf16 [M*K] | Bt bf16 [N*K]  (160 MB total).
// ---------------------------------------------------------------------------

typedef __attribute__((ext_vector_type(8))) short short8;   // 8 x bf16 frag
typedef __attribute__((ext_vector_type(4))) float f32x4;
typedef unsigned short ushort_t;

// fp32 -> fp8 e4m3fn (RNE, HW) -> fp32. gfx950 uses OCP e4m3fn.
__device__ __forceinline__ float fp8_round_trip(float v) {
    int p = __builtin_amdgcn_cvt_pk_fp8_f32(v, v, 0, false);
    return __builtin_amdgcn_cvt_f32_fp8(p, 0);
}

// fp32 -> bf16 RNE (values are finite; no NaN path needed)
__device__ __forceinline__ ushort_t f32_to_bf16(float f) {
    union { float f; unsigned u; } un; un.f = f;
    unsigned r = un.u + 0x7fffu + ((un.u >> 16) & 1u);
    return (ushort_t)(r >> 16);
}

// async 16B/lane global -> LDS (wave-uniform LDS base + lane*16)
__device__ __forceinline__ void async16(const void* g, void* l) {
    __builtin_amdgcn_global_load_lds(
        (const __attribute__((address_space(1))) unsigned int*)g,
        (__attribute__((address_space(3))) unsigned int*)l,
        16, 0, 0);
}

// ---------------------------------------------------------------------------
// quant_x: x[M,K] f32 -> Xd[M,K] bf16 (dequantized). One 128-elem fp8 block
// per 32-lane half-wave; each lane handles one float4 (4 elems).
// ---------------------------------------------------------------------------
__global__ __launch_bounds__(256) void quant_x_kernel(
        const float* __restrict__ x, ushort_t* __restrict__ xd) {
    size_t tid  = (size_t)blockIdx.x * 256 + threadIdx.x;
    size_t base = tid * 4;
    float4 v = *(const float4*)(x + base);
    float amax = fmaxf(fmaxf(fabsf(v.x), fabsf(v.y)),
                       fmaxf(fabsf(v.z), fabsf(v.w)));
    // reduce over the 32-lane half (covers exactly 128 consecutive elements)
    #pragma unroll
    for (int m = 1; m < 32; m <<= 1)
        amax = fmaxf(amax, __shfl_xor(amax, m, 64));
    float scale = fmaxf(amax / 448.0f, 1e-12f);
    ushort4 o;
    o.x = f32_to_bf16(fp8_round_trip(v.x / scale) * scale);
    o.y = f32_to_bf16(fp8_round_trip(v.y / scale) * scale);
    o.z = f32_to_bf16(fp8_round_trip(v.z / scale) * scale);
    o.w = f32_to_bf16(fp8_round_trip(v.w / scale) * scale);
    *(ushort4*)(xd + base) = o;
}

// ---------------------------------------------------------------------------
// quant_w: w[K,N] f32 -> Bt[N,K] bf16 (dequantized + transposed).
// Tile: 64 k-rows x 128 n-cols (one fp8 block per row). Block = 256 threads.
// Each 32-lane half-wave quantizes one row (float4/lane), stores dequantized
// f32 to LDS transposed [n][k] (stride 65 to dodge bank conflicts), then the
// block writes Bt coalesced (ushort4 along K).
// ---------------------------------------------------------------------------
__global__ __launch_bounds__(256) void quant_w_kernel(
        const float* __restrict__ w, ushort_t* __restrict__ bt,
        int K, int N) {
    __shared__ float lds[128 * 65];
    int k0 = blockIdx.x * 64;
    int n0 = blockIdx.y * 128;
    int t = threadIdx.x;
    int wid = t >> 6, lane = t & 63;
    int half = lane >> 5, l32 = lane & 31;

    #pragma unroll
    for (int rr = 0; rr < 8; ++rr) {
        int klocal = wid * 16 + rr * 2 + half;   // 0..63, each once
        int k = k0 + klocal;
        float4 v = *(const float4*)(w + (size_t)k * N + n0 + l32 * 4);
        float amax = fmaxf(fmaxf(fabsf(v.x), fabsf(v.y)),
                           fmaxf(fabsf(v.z), fabsf(v.w)));
        #pragma unroll
        for (int m = 1; m < 32; m <<= 1)
            amax = fmaxf(amax, __shfl_xor(amax, m, 64));
        float scale = fmaxf(amax / 448.0f, 1e-12f);
        int nl = l32 * 4;
        lds[(nl + 0) * 65 + klocal] = fp8_round_trip(v.x / scale) * scale;
        lds[(nl + 1) * 65 + klocal] = fp8_round_trip(v.y / scale) * scale;
        lds[(nl + 2) * 65 + klocal] = fp8_round_trip(v.z / scale) * scale;
        lds[(nl + 3) * 65 + klocal] = fp8_round_trip(v.w / scale) * scale;
    }
    __syncthreads();
    // write 128 rows x 64 cols bf16, ushort4 per thread per iter
    #pragma unroll
    for (int it = 0; it < 8; ++it) {
        int idx = it * 256 + t;      // 0..2047
        int j = idx >> 4;            // n-row 0..127
        int c = idx & 15;            // k-chunk (4 elems)
        const float* p = &lds[j * 65 + c * 4];
        ushort4 o;
        o.x = f32_to_bf16(p[0]);
        o.y = f32_to_bf16(p[1]);
        o.z = f32_to_bf16(p[2]);
        o.w = f32_to_bf16(p[3]);
        *(ushort4*)(bt + (size_t)(n0 + j) * K + k0 + c * 4) = o;
    }
}

// ---------------------------------------------------------------------------
// gemm_bt: C[M,N] = A[M,K](bf16) * Bt[N,K](bf16)^T + bias.  m97 structure:
// 128x128 tile, BK=32, 256 threads (4 waves, 2x2), mfma_f32_16x16x32_bf16,
// 4x4 accumulator tiles per wave, global_load_lds width=16 staging.
// ---------------------------------------------------------------------------
__global__ __launch_bounds__(256) void gemm_bt_kernel(
        const ushort_t* __restrict__ A, const ushort_t* __restrict__ B,
        const float* __restrict__ bias, float* __restrict__ C,
        int M, int N, int K) {
    __shared__ ushort_t sA[128 * 32];   // 8 KB
    __shared__ ushort_t sB[128 * 32];   // 8 KB

    int t = threadIdx.x;
    int wv = t >> 6, lane = t & 63;
    int wr = wv >> 1, wc = wv & 1;
    int quad = lane >> 4, l16 = lane & 15;
    int bm = blockIdx.y, bn = blockIdx.x;

    f32x4 acc[4][4] = {};

    // staging map: thread t -> row t>>2 (and +64), col (t&3)*8 ushorts
    int srow = t >> 2;
    int scol = (t & 3) * 8;
    const ushort_t* gA = A + (size_t)(bm * 128 + srow) * K + scol;
    const ushort_t* gB = B + (size_t)(bn * 128 + srow) * K + scol;
    ushort_t* lA = sA + wv * 512;   // wave-uniform LDS base (bytes: wv*1024)
    ushort_t* lB = sB + wv * 512;

    for (int k0 = 0; k0 < K; k0 += 32) {
        __syncthreads();   // previous iteration's LDS reads complete
        async16(gA + k0,                  lA);
        async16(gA + k0 + (size_t)64 * K, lA + 64 * 32);
        async16(gB + k0,                  lB);
        async16(gB + k0 + (size_t)64 * K, lB + 64 * 32);
        __syncthreads();   // staging (vmcnt) drained before fragment reads

        short8 af[4], bfr[4];
        #pragma unroll
        for (int mt = 0; mt < 4; ++mt)
            af[mt] = *(const short8*)(sA + (wr * 64 + mt * 16 + l16) * 32 + quad * 8);
        #pragma unroll
        for (int nt = 0; nt < 4; ++nt)
            bfr[nt] = *(const short8*)(sB + (wc * 64 + nt * 16 + l16) * 32 + quad * 8);

        #pragma unroll
        for (int mt = 0; mt < 4; ++mt)
            #pragma unroll
            for (int nt = 0; nt < 4; ++nt)
                acc[mt][nt] = __builtin_amdgcn_mfma_f32_16x16x32_bf16(
                    af[mt], bfr[nt], acc[mt][nt], 0, 0, 0);
    }

    // epilogue: C/D layout col = lane&15, row = quad*4 + reg (m89/m91)
    #pragma unroll
    for (int nt = 0; nt < 4; ++nt) {
        int col = bn * 128 + wc * 64 + nt * 16 + l16;
        float bv = bias[col];
        #pragma unroll
        for (int mt = 0; mt < 4; ++mt) {
            int row0 = bm * 128 + wr * 64 + mt * 16 + quad * 4;
            #pragma unroll
            for (int r = 0; r < 4; ++r)
                C[(size_t)(row0 + r) * N + col] = acc[mt][nt][r] + bv;
        }
    }
}

// ---------------------------------------------------------------------------
extern "C" void kernel_launch(void* const* d_in, const int* in_sizes, int n_in,
                              void* d_out, int out_size, void* d_ws, size_t ws_size,
                              hipStream_t stream) {
    const float* x    = (const float*)d_in[0];
    const float* w    = (const float*)d_in[1];
    const float* bias = (const float*)d_in[2];
    float* out = (float*)d_out;

    const int N = in_sizes[2];              // 4096
    const int K = in_sizes[1] / N;          // 4096
    const int M = in_sizes[0] / K;          // 16384

    ushort_t* xd = (ushort_t*)d_ws;                  // M*K bf16
    ushort_t* bt = xd + (size_t)M * K;               // N*K bf16
    // requires ws_size >= (M*K + N*K)*2 = 160 MB

    quant_x_kernel<<<(size_t)M * K / 1024, 256, 0, stream>>>(x, xd);
    quant_w_kernel<<<dim3(K / 64, N / 128), 256, 0, stream>>>(w, bt, K, N);
    gemm_bt_kernel<<<dim3(N / 128, M / 128), 256, 0, stream>>>(xd, bt, bias, out, M, N, K);
}